// Round 10
// baseline (951.454 us; speedup 1.0000x reference)
//
#include <hip/hip_runtime.h>
#include <hip/hip_cooperative_groups.h>
#include <math.h>

namespace cg = cooperative_groups;

#define N_NODES 50000
#define M_PAD   50048    // 391 * 128
#define E_EDGES 800000
#define IN_CH   128
#define C_CH    32
#define H_HEADS 8
#define HC      256      // H_HEADS * C_CH
#define BN_EPS  1e-5f
#define SLOPE   0.2f

#define CSR_BLOCKS  1024
#define CSR_THREADS 256
#define N_CHUNKS    ((N_NODES + CSR_THREADS - 1) / CSR_THREADS)   // 196

typedef _Float16 f16x8 __attribute__((ext_vector_type(8)));
typedef _Float16 f16x4 __attribute__((ext_vector_type(4)));
typedef _Float16 f16x2 __attribute__((ext_vector_type(2)));
typedef float    f32x4 __attribute__((ext_vector_type(4)));

// ---------------- cooperative CSR build + weight prep (single launch) ----------------
// Replaces 7 small launches (init/hist/scan x3/fill/split_w) with one kernel;
// phases separated by grid.sync(). 1024 blocks x 256 thr = 4 blocks/CU (co-resident).

__global__ void k_csr_prep(const int* __restrict__ src, const int* __restrict__ dst,
                           const float* __restrict__ Wl0, const float* __restrict__ Wr0,
                           const float* __restrict__ Wl1, const float* __restrict__ Wr1,
                           _Float16* __restrict__ W0lt, _Float16* __restrict__ W0rt,
                           _Float16* __restrict__ W1lt, _Float16* __restrict__ W1rt,
                           int* __restrict__ deg, int* __restrict__ row_ptr,
                           int* __restrict__ cursor, int* __restrict__ partials,
                           int* __restrict__ csr_src) {
    cg::grid_group grid = cg::this_grid();
    __shared__ int sm[CSR_THREADS];
    int t = threadIdx.x;
    int gid = blockIdx.x * CSR_THREADS + t;
    const int gsz = CSR_BLOCKS * CSR_THREADS;   // 262144

    // phase 1: deg = 1 (self-loop); weight transpose W[K,256] -> Wt f16 [256][K]
    for (int i = gid; i < N_NODES; i += gsz) deg[i] = 1;
    for (int w = gid; w < 196608; w += gsz) {
        const float* W; _Float16* O; int K, rel;
        if (w < 32768)       { W = Wl0; O = W0lt; K = 128; rel = w; }
        else if (w < 65536)  { W = Wr0; O = W0rt; K = 128; rel = w - 32768; }
        else if (w < 131072) { W = Wl1; O = W1lt; K = 256; rel = w - 65536; }
        else                 { W = Wr1; O = W1rt; K = 256; rel = w - 131072; }
        int n = rel / K, k = rel - n * K;
        O[rel] = (_Float16)W[(size_t)k * 256 + n];
    }
    grid.sync();

    // phase 2: degree histogram
    for (int e = gid; e < E_EDGES; e += gsz) atomicAdd(&deg[dst[e]], 1);
    grid.sync();

    // phase 3a: per-chunk exclusive scan (N_CHUNKS chunks of 256)
    if (blockIdx.x < N_CHUNKS) {
        int i = blockIdx.x * CSR_THREADS + t;
        int v = (i < N_NODES) ? deg[i] : 0;
        sm[t] = v;
        __syncthreads();
        #pragma unroll
        for (int off = 1; off < CSR_THREADS; off <<= 1) {
            int u = (t >= off) ? sm[t - off] : 0;
            __syncthreads();
            sm[t] += u;
            __syncthreads();
        }
        if (i < N_NODES) row_ptr[i] = sm[t] - v;
        if (t == CSR_THREADS - 1) partials[blockIdx.x] = sm[t];
    }
    grid.sync();

    // phase 3b: block 0 scans the chunk sums
    if (blockIdx.x == 0) {
        int v = (t < N_CHUNKS) ? partials[t] : 0;
        sm[t] = v;
        __syncthreads();
        #pragma unroll
        for (int off = 1; off < CSR_THREADS; off <<= 1) {
            int u = (t >= off) ? sm[t - off] : 0;
            __syncthreads();
            sm[t] += u;
            __syncthreads();
        }
        if (t < N_CHUNKS) partials[t] = sm[t] - v;   // exclusive
        if (t == 0) row_ptr[N_NODES] = E_EDGES + N_NODES;
    }
    grid.sync();

    // phase 3c: add chunk offsets -> row_ptr, cursor
    for (int i = gid; i < N_NODES; i += gsz) {
        int v = row_ptr[i] + partials[i >> 8];
        row_ptr[i] = v;
        cursor[i] = v;
    }
    grid.sync();

    // phase 4: CSR fill (edges then self-loops)
    for (int e = gid; e < E_EDGES + N_NODES; e += gsz) {
        int s, d;
        if (e < E_EDGES) { s = src[e]; d = dst[e]; }
        else             { s = e - E_EDGES; d = s; }
        int p = atomicAdd(&cursor[d], 1);
        csr_src[p] = s;
    }
}

// ---------------- f16 MFMA GEMM (single term) ----------------
// z=0: C0 = A@W0 -> f16 xl table; z=1: C1 = A@W1 -> f16 xr table.
// A either f16 (A16) or f32 (A32, converted in staging; rows >= N_NODES -> 0).
// Tile: BM=128, BN=128, BK=32; 4 waves; wave w owns rows [w*32,w*32+32).
// mfma_f32_16x16x32_f16 layouts (m89/m91-verified):
//   A: m=lane&15, k=(lane>>4)*8+j   B: n=lane&15, k=(lane>>4)*8+j
//   C/D: col=lane&15, row=(lane>>4)*4+reg

#define BK  32
#define LDA 40   // LDS row pitch in f16 (32 + 8 pad -> 80 B, 16B-aligned)

__device__ __forceinline__ f16x8 cvt_h8(float4 a, float4 b) {
    f16x8 v = { (_Float16)a.x, (_Float16)a.y, (_Float16)a.z, (_Float16)a.w,
                (_Float16)b.x, (_Float16)b.y, (_Float16)b.z, (_Float16)b.w };
    return v;
}

__global__ __launch_bounds__(256) void k_gemm_mfma(
        const _Float16* __restrict__ A16, const float* __restrict__ A32,
        const _Float16* __restrict__ W0t, const _Float16* __restrict__ W1t,
        _Float16* __restrict__ C0, _Float16* __restrict__ C1, int K) {
    const _Float16* Wt = blockIdx.z ? W1t : W0t;
    _Float16* C = blockIdx.z ? C1 : C0;
    __shared__ _Float16 As[128 * LDA];
    __shared__ _Float16 Bs[128 * LDA];
    int t = threadIdx.x;
    int lane = t & 63, wv = t >> 6;
    int quad = lane >> 4, r16 = lane & 15;
    size_t mBase = (size_t)blockIdx.x * 128;
    size_t nBase = (size_t)blockIdx.y * 128;
    int sr = t >> 2;              // staging row 0..63
    int sc = (t & 3) * 8;         // staging col (f16 units)
    f32x4 acc[2][8] = {};
    for (int k0 = 0; k0 < K; k0 += BK) {
        if (A32) {
            size_t r0 = mBase + sr, r1 = r0 + 64;
            float4 a0 = {0.f,0.f,0.f,0.f}, a1 = a0, b0 = a0, b1 = a0;
            if (r0 < N_NODES) {
                const float* g = A32 + r0 * K + k0 + sc;
                a0 = ((const float4*)g)[0];
                a1 = ((const float4*)g)[1];
            }
            if (r1 < N_NODES) {
                const float* g = A32 + r1 * K + k0 + sc;
                b0 = ((const float4*)g)[0];
                b1 = ((const float4*)g)[1];
            }
            *(f16x8*)&As[sr * LDA + sc]        = cvt_h8(a0, a1);
            *(f16x8*)&As[(sr + 64) * LDA + sc] = cvt_h8(b0, b1);
        } else {
            const _Float16* gA = A16 + (mBase + sr) * K + k0 + sc;
            *(f16x8*)&As[sr * LDA + sc]        = *(const f16x8*)gA;
            *(f16x8*)&As[(sr + 64) * LDA + sc] = *(const f16x8*)(gA + (size_t)64 * K);
        }
        const _Float16* gB = Wt + (nBase + sr) * K + k0 + sc;
        *(f16x8*)&Bs[sr * LDA + sc]        = *(const f16x8*)gB;
        *(f16x8*)&Bs[(sr + 64) * LDA + sc] = *(const f16x8*)(gB + (size_t)64 * K);
        __syncthreads();
        f16x8 av[2];
        #pragma unroll
        for (int mi = 0; mi < 2; ++mi) {
            int m = wv * 32 + mi * 16 + r16;
            av[mi] = *(f16x8*)&As[m * LDA + quad * 8];
        }
        #pragma unroll
        for (int ni = 0; ni < 8; ++ni) {
            int n = ni * 16 + r16;
            f16x8 bv = *(f16x8*)&Bs[n * LDA + quad * 8];
            #pragma unroll
            for (int mi = 0; mi < 2; ++mi)
                acc[mi][ni] = __builtin_amdgcn_mfma_f32_16x16x32_f16(av[mi], bv, acc[mi][ni], 0, 0, 0);
        }
        __syncthreads();
    }
    #pragma unroll
    for (int mi = 0; mi < 2; ++mi)
        #pragma unroll
        for (int r = 0; r < 4; ++r) {
            size_t row = mBase + wv * 32 + mi * 16 + quad * 4 + r;
            _Float16* cp = C + row * 256 + nBase + r16;
            #pragma unroll
            for (int ni = 0; ni < 8; ++ni)
                cp[ni * 16] = (_Float16)acc[mi][ni][r];
        }
}

// ---------------- edge pass: one wave per node, 4 channels per lane ----------------
// xl and xr both f16 [node][256]; edge gather = 8 B/lane (512 B/wave).
// Logit pipeline in packed f16: v_pk_add / v_pk_mul / v_pk_max + v_dot2_f32_f16.

__device__ __forceinline__ float edge_w16(f16x4 h, f16x4 xr, f16x4 att) {
    f16x4 e = h + xr;                                    // 2x v_pk_add_f16
    f16x4 es = e * (_Float16)SLOPE;                      // 2x v_pk_mul_f16
    f16x4 l = __builtin_elementwise_max(e, es);          // 2x v_pk_max_f16 (slope<1)
#if __has_builtin(__builtin_amdgcn_fdot2)
    f16x2 l01 = __builtin_shufflevector(l, l, 0, 1);
    f16x2 l23 = __builtin_shufflevector(l, l, 2, 3);
    f16x2 a01 = __builtin_shufflevector(att, att, 0, 1);
    f16x2 a23 = __builtin_shufflevector(att, att, 2, 3);
    float p = __builtin_amdgcn_fdot2(l01, a01, 0.f, false);
    p = __builtin_amdgcn_fdot2(l23, a23, p, false);
#else
    float p = (float)l[0] * (float)att[0];
    p = fmaf((float)l[1], (float)att[1], p);
    p = fmaf((float)l[2], (float)att[2], p);
    p = fmaf((float)l[3], (float)att[3], p);
#endif
    p += __shfl_xor(p, 1);
    p += __shfl_xor(p, 2);
    p += __shfl_xor(p, 4);
    return __expf(p);
}

__device__ __forceinline__ float4 edge_accum(
        const f16x4* __restrict__ xl4, f16x4 xr_h, f16x4 att_h,
        const int* __restrict__ csr_src, int beg, int end, int lane) {
    const f16x4* xlp = xl4 + lane;          // lane-biased base: addr = s*512B
    float4 acc = {0.f, 0.f, 0.f, 0.f};
    float S = 0.f;
    int j = beg;
    for (; j + 4 <= end; j += 4) {
        int s0 = csr_src[j];
        int s1 = csr_src[j + 1];
        int s2 = csr_src[j + 2];
        int s3 = csr_src[j + 3];
        f16x4 h0 = xlp[(size_t)s0 * 64];
        f16x4 h1 = xlp[(size_t)s1 * 64];
        f16x4 h2 = xlp[(size_t)s2 * 64];
        f16x4 h3 = xlp[(size_t)s3 * 64];
        float w0 = edge_w16(h0, xr_h, att_h);
        float w1 = edge_w16(h1, xr_h, att_h);
        float w2 = edge_w16(h2, xr_h, att_h);
        float w3 = edge_w16(h3, xr_h, att_h);
        S += (w0 + w1) + (w2 + w3);
        acc.x = fmaf((float)h0[0], w0, acc.x); acc.y = fmaf((float)h0[1], w0, acc.y);
        acc.z = fmaf((float)h0[2], w0, acc.z); acc.w = fmaf((float)h0[3], w0, acc.w);
        acc.x = fmaf((float)h1[0], w1, acc.x); acc.y = fmaf((float)h1[1], w1, acc.y);
        acc.z = fmaf((float)h1[2], w1, acc.z); acc.w = fmaf((float)h1[3], w1, acc.w);
        acc.x = fmaf((float)h2[0], w2, acc.x); acc.y = fmaf((float)h2[1], w2, acc.y);
        acc.z = fmaf((float)h2[2], w2, acc.z); acc.w = fmaf((float)h2[3], w2, acc.w);
        acc.x = fmaf((float)h3[0], w3, acc.x); acc.y = fmaf((float)h3[1], w3, acc.y);
        acc.z = fmaf((float)h3[2], w3, acc.z); acc.w = fmaf((float)h3[3], w3, acc.w);
    }
    for (; j < end; ++j) {
        int s = csr_src[j];
        f16x4 hv = xlp[(size_t)s * 64];
        float w = edge_w16(hv, xr_h, att_h);
        S += w;
        acc.x = fmaf((float)hv[0], w, acc.x); acc.y = fmaf((float)hv[1], w, acc.y);
        acc.z = fmaf((float)hv[2], w, acc.z); acc.w = fmaf((float)hv[3], w, acc.w);
    }
    float inv = 1.f / S;
    acc.x *= inv; acc.y *= inv; acc.z *= inv; acc.w *= inv;
    return acc;
}

__device__ __forceinline__ f16x4 cvt_h4(float4 v) {
    f16x4 r = { (_Float16)v.x, (_Float16)v.y, (_Float16)v.z, (_Float16)v.w };
    return r;
}

// layer 0: concat + bias + BN + ELU -> h0 (f16).
__global__ __launch_bounds__(256) void k_edge0(
        const _Float16* __restrict__ xl, const _Float16* __restrict__ xr,
        const float* __restrict__ att,
        const int* __restrict__ row_ptr, const int* __restrict__ csr_src,
        const float* __restrict__ b0, const float* __restrict__ g0,
        const float* __restrict__ be0, const float* __restrict__ m0,
        const float* __restrict__ v0,
        _Float16* __restrict__ h0) {
    int lane = threadIdx.x & 63;
    int i = blockIdx.x * 4 + (threadIdx.x >> 6);
    const f16x4* xl4 = (const f16x4*)xl;
    f16x4 xr_h = ((const f16x4*)xr)[(size_t)i * 64 + lane];
    f16x4 att_h = cvt_h4(((const float4*)att)[lane]);
    int beg = row_ptr[i], end = row_ptr[i + 1];
    float4 r = edge_accum(xl4, xr_h, att_h, csr_src, beg, end, lane);
    float4 bb = ((const float4*)b0)[lane];
    float4 gg = ((const float4*)g0)[lane];
    float4 ee = ((const float4*)be0)[lane];
    float4 mm = ((const float4*)m0)[lane];
    float4 vv = ((const float4*)v0)[lane];
    float4 o;
    o.x = (r.x + bb.x - mm.x) * rsqrtf(vv.x + BN_EPS) * gg.x + ee.x;
    o.y = (r.y + bb.y - mm.y) * rsqrtf(vv.y + BN_EPS) * gg.y + ee.y;
    o.z = (r.z + bb.z - mm.z) * rsqrtf(vv.z + BN_EPS) * gg.z + ee.z;
    o.w = (r.w + bb.w - mm.w) * rsqrtf(vv.w + BN_EPS) * gg.w + ee.w;
    o.x = o.x > 0.f ? o.x : expm1f(o.x);
    o.y = o.y > 0.f ? o.y : expm1f(o.y);
    o.z = o.z > 0.f ? o.z : expm1f(o.z);
    o.w = o.w > 0.f ? o.w : expm1f(o.w);
    f16x4 hh = { (_Float16)o.x, (_Float16)o.y, (_Float16)o.z, (_Float16)o.w };
    ((f16x4*)h0)[(size_t)i * 64 + lane] = hh;
}

// layer 1: head-mean + bias + BN + classifier, fully in-register.
__global__ __launch_bounds__(256) void k_edge1(
        const _Float16* __restrict__ xl, const _Float16* __restrict__ xr,
        const float* __restrict__ att,
        const int* __restrict__ row_ptr, const int* __restrict__ csr_src,
        const float* __restrict__ b1, const float* __restrict__ g1,
        const float* __restrict__ be1, const float* __restrict__ m1,
        const float* __restrict__ v1,
        const float* __restrict__ Wc, const float* __restrict__ bc,
        float* __restrict__ out) {
    int lane = threadIdx.x & 63;
    int q = lane & 7;
    int i = blockIdx.x * 4 + (threadIdx.x >> 6);
    const f16x4* xl4 = (const f16x4*)xl;
    f16x4 xr_h = ((const f16x4*)xr)[(size_t)i * 64 + lane];
    f16x4 att_h = cvt_h4(((const float4*)att)[lane]);
    int beg = row_ptr[i], end = row_ptr[i + 1];
    float4 r = edge_accum(xl4, xr_h, att_h, csr_src, beg, end, lane);
    #pragma unroll
    for (int mask = 8; mask <= 32; mask <<= 1) {
        r.x += __shfl_xor(r.x, mask);
        r.y += __shfl_xor(r.y, mask);
        r.z += __shfl_xor(r.z, mask);
        r.w += __shfl_xor(r.w, mask);
    }
    float4 bb = ((const float4*)b1)[q];
    float4 gg = ((const float4*)g1)[q];
    float4 ee = ((const float4*)be1)[q];
    float4 mm = ((const float4*)m1)[q];
    float4 vv = ((const float4*)v1)[q];
    r.x = (r.x * 0.125f + bb.x - mm.x) * rsqrtf(vv.x + BN_EPS) * gg.x + ee.x;
    r.y = (r.y * 0.125f + bb.y - mm.y) * rsqrtf(vv.y + BN_EPS) * gg.y + ee.y;
    r.z = (r.z * 0.125f + bb.z - mm.z) * rsqrtf(vv.z + BN_EPS) * gg.z + ee.z;
    r.w = (r.w * 0.125f + bb.w - mm.w) * rsqrtf(vv.w + BN_EPS) * gg.w + ee.w;
    float4 wc0 = ((const float4*)Wc)[q * 2];
    float4 wc1 = ((const float4*)Wc)[q * 2 + 1];
    float o0 = r.x * wc0.x + r.y * wc0.z + r.z * wc1.x + r.w * wc1.z;
    float o1 = r.x * wc0.y + r.y * wc0.w + r.z * wc1.y + r.w * wc1.w;
    #pragma unroll
    for (int mask = 1; mask <= 4; mask <<= 1) {
        o0 += __shfl_xor(o0, mask);
        o1 += __shfl_xor(o1, mask);
    }
    if (lane == 0) {
        float2 ov = {o0 + bc[0], o1 + bc[1]};
        *(float2*)(out + (size_t)i * 2) = ov;
    }
}

// ---------------- launcher ----------------

extern "C" void kernel_launch(void* const* d_in, const int* in_sizes, int n_in,
                              void* d_out, int out_size, void* d_ws, size_t ws_size,
                              hipStream_t stream) {
    const float* x    = (const float*)d_in[0];
    const int*   ei   = (const int*)d_in[1];
    const float* Wl0  = (const float*)d_in[2];
    const float* Wr0  = (const float*)d_in[3];
    const float* att0 = (const float*)d_in[4];
    const float* b0   = (const float*)d_in[5];
    const float* g0   = (const float*)d_in[6];
    const float* be0  = (const float*)d_in[7];
    const float* m0   = (const float*)d_in[8];
    const float* v0   = (const float*)d_in[9];
    const float* Wl1  = (const float*)d_in[10];
    const float* Wr1  = (const float*)d_in[11];
    const float* att1 = (const float*)d_in[12];
    const float* b1   = (const float*)d_in[13];
    const float* g1   = (const float*)d_in[14];
    const float* be1  = (const float*)d_in[15];
    const float* m1   = (const float*)d_in[16];
    const float* v1   = (const float*)d_in[17];
    const float* Wc   = (const float*)d_in[18];
    const float* bc   = (const float*)d_in[19];
    float* out = (float*)d_out;

    const int* srcp = ei;        // edge_index[0]
    const int* dstp = ei + E_EDGES;    // edge_index[1]

    // workspace carve-up (16B-aligned chunks)
    char* p = (char*)d_ws;
    _Float16* xlf = (_Float16*)p; p += (size_t)M_PAD * HC * 2;   // xl table [M_PAD,256] f16
    _Float16* xrf = (_Float16*)p; p += (size_t)M_PAD * HC * 2;   // xr table [M_PAD,256] f16
    _Float16* h0  = (_Float16*)p; p += (size_t)M_PAD * HC * 2;   // h0 [M_PAD,256] f16
    _Float16* W0lt = (_Float16*)p; p += (size_t)HC * IN_CH * 2;  // Wt of Wl0 [256][128]
    _Float16* W0rt = (_Float16*)p; p += (size_t)HC * IN_CH * 2;
    _Float16* W1lt = (_Float16*)p; p += (size_t)HC * HC * 2;     // Wt of Wl1 [256][256]
    _Float16* W1rt = (_Float16*)p; p += (size_t)HC * HC * 2;
    int* deg      = (int*)p;
    int* row_ptr  = deg + N_NODES;
    int* cursor   = row_ptr + (N_NODES + 1);
    int* partials = cursor + N_NODES;
    int* csr_src  = partials + ((N_CHUNKS + 3) & ~3);   // E+N entries

    // CSR build + weight prep: single cooperative launch
    {
        void* args[] = {
            (void*)&srcp, (void*)&dstp,
            (void*)&Wl0, (void*)&Wr0, (void*)&Wl1, (void*)&Wr1,
            (void*)&W0lt, (void*)&W0rt, (void*)&W1lt, (void*)&W1rt,
            (void*)&deg, (void*)&row_ptr, (void*)&cursor, (void*)&partials,
            (void*)&csr_src,
        };
        hipLaunchCooperativeKernel((const void*)k_csr_prep,
                                   dim3(CSR_BLOCKS), dim3(CSR_THREADS),
                                   args, 0, stream);
    }

    dim3 ggrid(M_PAD / 128, 2, 2);
    // layer 0 projections: xl0 = x@Wl0, xr0 = x@Wr0 (f32 A converted in staging)
    k_gemm_mfma<<<ggrid, 256, 0, stream>>>(nullptr, x, W0lt, W0rt, xlf, xrf, IN_CH);
    // layer 0 edge pass + BN + ELU -> h0 (f16)
    k_edge0<<<N_NODES / 4, 256, 0, stream>>>(xlf, xrf, att0, row_ptr, csr_src,
                                             b0, g0, be0, m0, v0, h0);
    // layer 1 projections: xl1 = h0@Wl1, xr1 = h0@Wr1
    k_gemm_mfma<<<ggrid, 256, 0, stream>>>(h0, nullptr, W1lt, W1rt, xlf, xrf, HC);
    // layer 1 edge pass + head-mean + BN + classifier -> out
    k_edge1<<<N_NODES / 4, 256, 0, stream>>>(xlf, xrf, att1, row_ptr, csr_src,
                                             b1, g1, be1, m1, v1, Wc, bc, out);
}

// Round 11
// 410.680 us; speedup vs baseline: 2.3168x; 2.3168x over previous
//
#include <hip/hip_runtime.h>
#include <math.h>

#define N_NODES 50000
#define M_PAD   50048    // 391 * 128
#define E_EDGES 800000
#define IN_CH   128
#define C_CH    32
#define H_HEADS 8
#define HC      256      // H_HEADS * C_CH
#define BN_EPS  1e-5f
#define SLOPE   0.2f

#define SCAN_CHUNK 512
#define SCAN_B     ((N_NODES + SCAN_CHUNK - 1) / SCAN_CHUNK)   // 98

typedef _Float16 f16x8 __attribute__((ext_vector_type(8)));
typedef _Float16 f16x4 __attribute__((ext_vector_type(4)));
typedef _Float16 f16x2 __attribute__((ext_vector_type(2)));
typedef float    f32x4 __attribute__((ext_vector_type(4)));

// ---------------- CSR build ----------------
// deg[] is zeroed via hipMemsetAsync; holds edge-only in-degree. The self-loop
// "+1" is folded into the scan read below.

__global__ void k_hist(const int* __restrict__ dst, int* deg, int e) {
    int i = blockIdx.x * blockDim.x + threadIdx.x;
    if (i < e) atomicAdd(&deg[dst[i]], 1);
}

// stage 1: per-chunk (512 elems) exclusive scan of (deg[i]+1) + chunk sum
__global__ __launch_bounds__(256) void k_scan_local(
        const int* __restrict__ deg, int* __restrict__ row_ptr,
        int* __restrict__ partials, int n) {
    __shared__ int sm[256];
    int t = threadIdx.x;
    int base = blockIdx.x * SCAN_CHUNK;
    int i0 = base + 2 * t, i1 = i0 + 1;
    int a = (i0 < n) ? deg[i0] + 1 : 0;   // +1 self-loop
    int b = (i1 < n) ? deg[i1] + 1 : 0;
    int s = a + b;
    sm[t] = s;
    __syncthreads();
    #pragma unroll
    for (int off = 1; off < 256; off <<= 1) {
        int u = (t >= off) ? sm[t - off] : 0;
        __syncthreads();
        sm[t] += u;
        __syncthreads();
    }
    int excl = sm[t] - s;               // exclusive prefix of pair-sums
    if (i0 < n) row_ptr[i0] = excl;
    if (i1 < n) row_ptr[i1] = excl + a;
    if (t == 255) partials[blockIdx.x] = sm[255];
}

// stage 2 (merged): every block redundantly scans the 98 chunk sums in LDS
// (trivial) and applies its chunk offset; writes row_ptr and cursor.
__global__ __launch_bounds__(256) void k_scan_finish(
        int* __restrict__ row_ptr, int* __restrict__ cursor,
        const int* __restrict__ partials, int n) {
    __shared__ int sm[256];
    int t = threadIdx.x;
    int v = (t < SCAN_B) ? partials[t] : 0;
    sm[t] = v;
    __syncthreads();
    #pragma unroll
    for (int off = 1; off < 256; off <<= 1) {
        int u = (t >= off) ? sm[t - off] : 0;
        __syncthreads();
        sm[t] += u;
        __syncthreads();
    }
    int i = blockIdx.x * 256 + t;
    // exclusive prefix of partials for chunk c is sm[c] - partials[c]
    if (i < n) {
        int c = i >> 9;                       // i / SCAN_CHUNK
        int off = sm[c] - partials[c];
        int val = row_ptr[i] + off;
        row_ptr[i] = val;
        cursor[i] = val;
    }
    if (blockIdx.x == 0 && t == 0) row_ptr[n] = E_EDGES + N_NODES;
}

__global__ void k_fill(const int* __restrict__ src, const int* __restrict__ dst,
                       int* cursor, int* csr_src, int e, int n) {
    int i = blockIdx.x * blockDim.x + threadIdx.x;
    if (i < e) {
        int d = dst[i];
        int p = atomicAdd(&cursor[d], 1);
        csr_src[p] = src[i];
    } else if (i < e + n) {
        int v = i - e;                  // self loop
        int p = atomicAdd(&cursor[v], 1);
        csr_src[p] = v;
    }
}

// ---------------- weight prep: all 4 W [K,256] -> Wt f16 [256][K] ----------------

__global__ void k_split_w4(const float* __restrict__ Wl0, const float* __restrict__ Wr0,
                           const float* __restrict__ Wl1, const float* __restrict__ Wr1,
                           _Float16* __restrict__ W0lt, _Float16* __restrict__ W0rt,
                           _Float16* __restrict__ W1lt, _Float16* __restrict__ W1rt) {
    int t = blockIdx.x * blockDim.x + threadIdx.x;
    const float* W; _Float16* O; int K, rel;
    if (t < 32768)       { W = Wl0; O = W0lt; K = 128; rel = t; }
    else if (t < 65536)  { W = Wr0; O = W0rt; K = 128; rel = t - 32768; }
    else if (t < 131072) { W = Wl1; O = W1lt; K = 256; rel = t - 65536; }
    else if (t < 196608) { W = Wr1; O = W1rt; K = 256; rel = t - 131072; }
    else return;
    int n = rel / K, k = rel - n * K;
    O[rel] = (_Float16)W[(size_t)k * 256 + n];
}

// ---------------- f16 MFMA GEMM (single term) ----------------
// z=0: C0 = A@W0 -> f16 xl table; z=1: C1 = A@W1 -> f16 xr table.
// A either f16 (A16) or f32 (A32, converted in staging; rows >= N_NODES -> 0).
// Tile: BM=128, BN=128, BK=32; 4 waves; wave w owns rows [w*32,w*32+32).
// mfma_f32_16x16x32_f16 layouts (m89/m91-verified):
//   A: m=lane&15, k=(lane>>4)*8+j   B: n=lane&15, k=(lane>>4)*8+j
//   C/D: col=lane&15, row=(lane>>4)*4+reg

#define BK  32
#define LDA 40   // LDS row pitch in f16 (32 + 8 pad -> 80 B, 16B-aligned)

__device__ __forceinline__ f16x8 cvt_h8(float4 a, float4 b) {
    f16x8 v = { (_Float16)a.x, (_Float16)a.y, (_Float16)a.z, (_Float16)a.w,
                (_Float16)b.x, (_Float16)b.y, (_Float16)b.z, (_Float16)b.w };
    return v;
}

__global__ __launch_bounds__(256) void k_gemm_mfma(
        const _Float16* __restrict__ A16, const float* __restrict__ A32,
        const _Float16* __restrict__ W0t, const _Float16* __restrict__ W1t,
        _Float16* __restrict__ C0, _Float16* __restrict__ C1, int K) {
    const _Float16* Wt = blockIdx.z ? W1t : W0t;
    _Float16* C = blockIdx.z ? C1 : C0;
    __shared__ _Float16 As[128 * LDA];
    __shared__ _Float16 Bs[128 * LDA];
    int t = threadIdx.x;
    int lane = t & 63, wv = t >> 6;
    int quad = lane >> 4, r16 = lane & 15;
    size_t mBase = (size_t)blockIdx.x * 128;
    size_t nBase = (size_t)blockIdx.y * 128;
    int sr = t >> 2;              // staging row 0..63
    int sc = (t & 3) * 8;         // staging col (f16 units)
    f32x4 acc[2][8] = {};
    for (int k0 = 0; k0 < K; k0 += BK) {
        if (A32) {
            size_t r0 = mBase + sr, r1 = r0 + 64;
            float4 a0 = {0.f,0.f,0.f,0.f}, a1 = a0, b0 = a0, b1 = a0;
            if (r0 < N_NODES) {
                const float* g = A32 + r0 * K + k0 + sc;
                a0 = ((const float4*)g)[0];
                a1 = ((const float4*)g)[1];
            }
            if (r1 < N_NODES) {
                const float* g = A32 + r1 * K + k0 + sc;
                b0 = ((const float4*)g)[0];
                b1 = ((const float4*)g)[1];
            }
            *(f16x8*)&As[sr * LDA + sc]        = cvt_h8(a0, a1);
            *(f16x8*)&As[(sr + 64) * LDA + sc] = cvt_h8(b0, b1);
        } else {
            const _Float16* gA = A16 + (mBase + sr) * K + k0 + sc;
            *(f16x8*)&As[sr * LDA + sc]        = *(const f16x8*)gA;
            *(f16x8*)&As[(sr + 64) * LDA + sc] = *(const f16x8*)(gA + (size_t)64 * K);
        }
        const _Float16* gB = Wt + (nBase + sr) * K + k0 + sc;
        *(f16x8*)&Bs[sr * LDA + sc]        = *(const f16x8*)gB;
        *(f16x8*)&Bs[(sr + 64) * LDA + sc] = *(const f16x8*)(gB + (size_t)64 * K);
        __syncthreads();
        f16x8 av[2];
        #pragma unroll
        for (int mi = 0; mi < 2; ++mi) {
            int m = wv * 32 + mi * 16 + r16;
            av[mi] = *(f16x8*)&As[m * LDA + quad * 8];
        }
        #pragma unroll
        for (int ni = 0; ni < 8; ++ni) {
            int n = ni * 16 + r16;
            f16x8 bv = *(f16x8*)&Bs[n * LDA + quad * 8];
            #pragma unroll
            for (int mi = 0; mi < 2; ++mi)
                acc[mi][ni] = __builtin_amdgcn_mfma_f32_16x16x32_f16(av[mi], bv, acc[mi][ni], 0, 0, 0);
        }
        __syncthreads();
    }
    #pragma unroll
    for (int mi = 0; mi < 2; ++mi)
        #pragma unroll
        for (int r = 0; r < 4; ++r) {
            size_t row = mBase + wv * 32 + mi * 16 + quad * 4 + r;
            _Float16* cp = C + row * 256 + nBase + r16;
            #pragma unroll
            for (int ni = 0; ni < 8; ++ni)
                cp[ni * 16] = (_Float16)acc[mi][ni][r];
        }
}

// ---------------- edge pass: one wave per node, 4 channels per lane ----------------
// xl and xr both f16 [node][256]; edge gather = 8 B/lane (512 B/wave).
// Logit pipeline in packed f16: v_pk_add / v_pk_mul / v_pk_max + v_dot2_f32_f16.

__device__ __forceinline__ float edge_w16(f16x4 h, f16x4 xr, f16x4 att) {
    f16x4 e = h + xr;                                    // 2x v_pk_add_f16
    f16x4 es = e * (_Float16)SLOPE;                      // 2x v_pk_mul_f16
    f16x4 l = __builtin_elementwise_max(e, es);          // 2x v_pk_max_f16 (slope<1)
#if __has_builtin(__builtin_amdgcn_fdot2)
    f16x2 l01 = __builtin_shufflevector(l, l, 0, 1);
    f16x2 l23 = __builtin_shufflevector(l, l, 2, 3);
    f16x2 a01 = __builtin_shufflevector(att, att, 0, 1);
    f16x2 a23 = __builtin_shufflevector(att, att, 2, 3);
    float p = __builtin_amdgcn_fdot2(l01, a01, 0.f, false);
    p = __builtin_amdgcn_fdot2(l23, a23, p, false);
#else
    float p = (float)l[0] * (float)att[0];
    p = fmaf((float)l[1], (float)att[1], p);
    p = fmaf((float)l[2], (float)att[2], p);
    p = fmaf((float)l[3], (float)att[3], p);
#endif
    p += __shfl_xor(p, 1);
    p += __shfl_xor(p, 2);
    p += __shfl_xor(p, 4);
    return __expf(p);
}

__device__ __forceinline__ float4 edge_accum(
        const f16x4* __restrict__ xl4, f16x4 xr_h, f16x4 att_h,
        const int* __restrict__ csr_src, int beg, int end, int lane) {
    const f16x4* xlp = xl4 + lane;          // lane-biased base: addr = s*512B
    float4 acc = {0.f, 0.f, 0.f, 0.f};
    float S = 0.f;
    int j = beg;
    for (; j + 4 <= end; j += 4) {
        int s0 = csr_src[j];
        int s1 = csr_src[j + 1];
        int s2 = csr_src[j + 2];
        int s3 = csr_src[j + 3];
        f16x4 h0 = xlp[(size_t)s0 * 64];
        f16x4 h1 = xlp[(size_t)s1 * 64];
        f16x4 h2 = xlp[(size_t)s2 * 64];
        f16x4 h3 = xlp[(size_t)s3 * 64];
        float w0 = edge_w16(h0, xr_h, att_h);
        float w1 = edge_w16(h1, xr_h, att_h);
        float w2 = edge_w16(h2, xr_h, att_h);
        float w3 = edge_w16(h3, xr_h, att_h);
        S += (w0 + w1) + (w2 + w3);
        acc.x = fmaf((float)h0[0], w0, acc.x); acc.y = fmaf((float)h0[1], w0, acc.y);
        acc.z = fmaf((float)h0[2], w0, acc.z); acc.w = fmaf((float)h0[3], w0, acc.w);
        acc.x = fmaf((float)h1[0], w1, acc.x); acc.y = fmaf((float)h1[1], w1, acc.y);
        acc.z = fmaf((float)h1[2], w1, acc.z); acc.w = fmaf((float)h1[3], w1, acc.w);
        acc.x = fmaf((float)h2[0], w2, acc.x); acc.y = fmaf((float)h2[1], w2, acc.y);
        acc.z = fmaf((float)h2[2], w2, acc.z); acc.w = fmaf((float)h2[3], w2, acc.w);
        acc.x = fmaf((float)h3[0], w3, acc.x); acc.y = fmaf((float)h3[1], w3, acc.y);
        acc.z = fmaf((float)h3[2], w3, acc.z); acc.w = fmaf((float)h3[3], w3, acc.w);
    }
    for (; j < end; ++j) {
        int s = csr_src[j];
        f16x4 hv = xlp[(size_t)s * 64];
        float w = edge_w16(hv, xr_h, att_h);
        S += w;
        acc.x = fmaf((float)hv[0], w, acc.x); acc.y = fmaf((float)hv[1], w, acc.y);
        acc.z = fmaf((float)hv[2], w, acc.z); acc.w = fmaf((float)hv[3], w, acc.w);
    }
    float inv = 1.f / S;
    acc.x *= inv; acc.y *= inv; acc.z *= inv; acc.w *= inv;
    return acc;
}

__device__ __forceinline__ f16x4 cvt_h4(float4 v) {
    f16x4 r = { (_Float16)v.x, (_Float16)v.y, (_Float16)v.z, (_Float16)v.w };
    return r;
}

// layer 0: concat + bias + BN + ELU -> h0 (f16).
__global__ __launch_bounds__(256) void k_edge0(
        const _Float16* __restrict__ xl, const _Float16* __restrict__ xr,
        const float* __restrict__ att,
        const int* __restrict__ row_ptr, const int* __restrict__ csr_src,
        const float* __restrict__ b0, const float* __restrict__ g0,
        const float* __restrict__ be0, const float* __restrict__ m0,
        const float* __restrict__ v0,
        _Float16* __restrict__ h0) {
    int lane = threadIdx.x & 63;
    int i = blockIdx.x * 4 + (threadIdx.x >> 6);
    const f16x4* xl4 = (const f16x4*)xl;
    f16x4 xr_h = ((const f16x4*)xr)[(size_t)i * 64 + lane];
    f16x4 att_h = cvt_h4(((const float4*)att)[lane]);
    int beg = row_ptr[i], end = row_ptr[i + 1];
    float4 r = edge_accum(xl4, xr_h, att_h, csr_src, beg, end, lane);
    float4 bb = ((const float4*)b0)[lane];
    float4 gg = ((const float4*)g0)[lane];
    float4 ee = ((const float4*)be0)[lane];
    float4 mm = ((const float4*)m0)[lane];
    float4 vv = ((const float4*)v0)[lane];
    float4 o;
    o.x = (r.x + bb.x - mm.x) * rsqrtf(vv.x + BN_EPS) * gg.x + ee.x;
    o.y = (r.y + bb.y - mm.y) * rsqrtf(vv.y + BN_EPS) * gg.y + ee.y;
    o.z = (r.z + bb.z - mm.z) * rsqrtf(vv.z + BN_EPS) * gg.z + ee.z;
    o.w = (r.w + bb.w - mm.w) * rsqrtf(vv.w + BN_EPS) * gg.w + ee.w;
    o.x = o.x > 0.f ? o.x : expm1f(o.x);
    o.y = o.y > 0.f ? o.y : expm1f(o.y);
    o.z = o.z > 0.f ? o.z : expm1f(o.z);
    o.w = o.w > 0.f ? o.w : expm1f(o.w);
    f16x4 hh = { (_Float16)o.x, (_Float16)o.y, (_Float16)o.z, (_Float16)o.w };
    ((f16x4*)h0)[(size_t)i * 64 + lane] = hh;
}

// layer 1: head-mean + bias + BN + classifier, fully in-register.
__global__ __launch_bounds__(256) void k_edge1(
        const _Float16* __restrict__ xl, const _Float16* __restrict__ xr,
        const float* __restrict__ att,
        const int* __restrict__ row_ptr, const int* __restrict__ csr_src,
        const float* __restrict__ b1, const float* __restrict__ g1,
        const float* __restrict__ be1, const float* __restrict__ m1,
        const float* __restrict__ v1,
        const float* __restrict__ Wc, const float* __restrict__ bc,
        float* __restrict__ out) {
    int lane = threadIdx.x & 63;
    int q = lane & 7;
    int i = blockIdx.x * 4 + (threadIdx.x >> 6);
    const f16x4* xl4 = (const f16x4*)xl;
    f16x4 xr_h = ((const f16x4*)xr)[(size_t)i * 64 + lane];
    f16x4 att_h = cvt_h4(((const float4*)att)[lane]);
    int beg = row_ptr[i], end = row_ptr[i + 1];
    float4 r = edge_accum(xl4, xr_h, att_h, csr_src, beg, end, lane);
    #pragma unroll
    for (int mask = 8; mask <= 32; mask <<= 1) {
        r.x += __shfl_xor(r.x, mask);
        r.y += __shfl_xor(r.y, mask);
        r.z += __shfl_xor(r.z, mask);
        r.w += __shfl_xor(r.w, mask);
    }
    float4 bb = ((const float4*)b1)[q];
    float4 gg = ((const float4*)g1)[q];
    float4 ee = ((const float4*)be1)[q];
    float4 mm = ((const float4*)m1)[q];
    float4 vv = ((const float4*)v1)[q];
    r.x = (r.x * 0.125f + bb.x - mm.x) * rsqrtf(vv.x + BN_EPS) * gg.x + ee.x;
    r.y = (r.y * 0.125f + bb.y - mm.y) * rsqrtf(vv.y + BN_EPS) * gg.y + ee.y;
    r.z = (r.z * 0.125f + bb.z - mm.z) * rsqrtf(vv.z + BN_EPS) * gg.z + ee.z;
    r.w = (r.w * 0.125f + bb.w - mm.w) * rsqrtf(vv.w + BN_EPS) * gg.w + ee.w;
    float4 wc0 = ((const float4*)Wc)[q * 2];
    float4 wc1 = ((const float4*)Wc)[q * 2 + 1];
    float o0 = r.x * wc0.x + r.y * wc0.z + r.z * wc1.x + r.w * wc1.z;
    float o1 = r.x * wc0.y + r.y * wc0.w + r.z * wc1.y + r.w * wc1.w;
    #pragma unroll
    for (int mask = 1; mask <= 4; mask <<= 1) {
        o0 += __shfl_xor(o0, mask);
        o1 += __shfl_xor(o1, mask);
    }
    if (lane == 0) {
        float2 ov = {o0 + bc[0], o1 + bc[1]};
        *(float2*)(out + (size_t)i * 2) = ov;
    }
}

// ---------------- launcher ----------------

extern "C" void kernel_launch(void* const* d_in, const int* in_sizes, int n_in,
                              void* d_out, int out_size, void* d_ws, size_t ws_size,
                              hipStream_t stream) {
    const float* x    = (const float*)d_in[0];
    const int*   ei   = (const int*)d_in[1];
    const float* Wl0  = (const float*)d_in[2];
    const float* Wr0  = (const float*)d_in[3];
    const float* att0 = (const float*)d_in[4];
    const float* b0   = (const float*)d_in[5];
    const float* g0   = (const float*)d_in[6];
    const float* be0  = (const float*)d_in[7];
    const float* m0   = (const float*)d_in[8];
    const float* v0   = (const float*)d_in[9];
    const float* Wl1  = (const float*)d_in[10];
    const float* Wr1  = (const float*)d_in[11];
    const float* att1 = (const float*)d_in[12];
    const float* b1   = (const float*)d_in[13];
    const float* g1   = (const float*)d_in[14];
    const float* be1  = (const float*)d_in[15];
    const float* m1   = (const float*)d_in[16];
    const float* v1   = (const float*)d_in[17];
    const float* Wc   = (const float*)d_in[18];
    const float* bc   = (const float*)d_in[19];
    float* out = (float*)d_out;

    const int N = N_NODES, E = E_EDGES;
    const int* srcp = ei;        // edge_index[0]
    const int* dstp = ei + E;    // edge_index[1]

    // workspace carve-up (16B-aligned chunks)
    char* p = (char*)d_ws;
    _Float16* xlf = (_Float16*)p; p += (size_t)M_PAD * HC * 2;   // xl table [M_PAD,256] f16
    _Float16* xrf = (_Float16*)p; p += (size_t)M_PAD * HC * 2;   // xr table [M_PAD,256] f16
    _Float16* h0  = (_Float16*)p; p += (size_t)M_PAD * HC * 2;   // h0 [M_PAD,256] f16
    _Float16* W0lt = (_Float16*)p; p += (size_t)HC * IN_CH * 2;  // Wt of Wl0 [256][128]
    _Float16* W0rt = (_Float16*)p; p += (size_t)HC * IN_CH * 2;
    _Float16* W1lt = (_Float16*)p; p += (size_t)HC * HC * 2;     // Wt of Wl1 [256][256]
    _Float16* W1rt = (_Float16*)p; p += (size_t)HC * HC * 2;
    int* deg      = (int*)p;
    int* row_ptr  = deg + N;
    int* cursor   = row_ptr + (N + 1);
    int* partials = cursor + N;
    int* csr_src  = partials + ((SCAN_B + 3) & ~3);   // E+N entries

    // CSR build (by dst): memset + 4 kernels
    hipMemsetAsync(deg, 0, (size_t)N * sizeof(int), stream);
    k_hist<<<(E + 255) / 256, 256, 0, stream>>>(dstp, deg, E);
    k_scan_local<<<SCAN_B, 256, 0, stream>>>(deg, row_ptr, partials, N);
    k_scan_finish<<<(N + 255) / 256, 256, 0, stream>>>(row_ptr, cursor, partials, N);
    k_fill<<<(E + N + 255) / 256, 256, 0, stream>>>(srcp, dstp, cursor, csr_src, E, N);

    // weight prep (single fused launch)
    k_split_w4<<<768, 256, 0, stream>>>(Wl0, Wr0, Wl1, Wr1, W0lt, W0rt, W1lt, W1rt);

    dim3 ggrid(M_PAD / 128, 2, 2);
    // layer 0 projections: xl0 = x@Wl0, xr0 = x@Wr0 (f32 A converted in staging)
    k_gemm_mfma<<<ggrid, 256, 0, stream>>>(nullptr, x, W0lt, W0rt, xlf, xrf, IN_CH);
    // layer 0 edge pass + BN + ELU -> h0 (f16)
    k_edge0<<<N / 4, 256, 0, stream>>>(xlf, xrf, att0, row_ptr, csr_src,
                                       b0, g0, be0, m0, v0, h0);
    // layer 1 projections: xl1 = h0@Wl1, xr1 = h0@Wr1
    k_gemm_mfma<<<ggrid, 256, 0, stream>>>(h0, nullptr, W1lt, W1rt, xlf, xrf, HC);
    // layer 1 edge pass + head-mean + BN + classifier -> out
    k_edge1<<<N / 4, 256, 0, stream>>>(xlf, xrf, att1, row_ptr, csr_src,
                                       b1, g1, be1, m1, v1, Wc, bc, out);
}